// Round 4
// baseline (138.439 us; speedup 1.0000x reference)
//
#include <hip/hip_runtime.h>
#include <math.h>

#define D 16
#define K 16
#define BLK 64
#define MPT 4             // 4 points/thread: amortizes param broadcast reads
#define PK_WORDS 96       // per-cluster param dwords (384 B)
// Param block per cluster k (dword units):
//   [0]      c_k           (f32)  log(pi_k) - sum(log diag L)
//   [1..16]  -t'_i         (f32)  t' = U' mu
//   [17..88] U' rows       (2xf16 packed, rows padded to even length; 72 words)
//   [89..95] zero pad

typedef _Float16 h2 __attribute__((ext_vector_type(2)));

__host__ __device__ constexpr int tri(int i, int j) { return i * (i + 1) / 2 + j; }
__host__ __device__ constexpr int rowoff(int i) {   // pair-offset of row i
    int s = 0;
    for (int r = 0; r < i; ++r) s += (r + 2) / 2;   // ceil((r+1)/2)
    return s;
}

static __device__ __forceinline__ float fdot2f(h2 a, h2 b, float c) {
#if __has_builtin(__builtin_amdgcn_fdot2)
    return __builtin_amdgcn_fdot2(a, b, c, false);  // 2 f16 MACs, f32 acc
#else
    return fmaf((float)a.x, (float)b.x, fmaf((float)a.y, (float)b.y, c));
#endif
}

static __device__ __forceinline__ unsigned pack2(float f0, float f1) {
    _Float16 h0 = (_Float16)f0, h1 = (_Float16)f1;  // RNE converts
    unsigned short b0 = __builtin_bit_cast(unsigned short, h0);
    unsigned short b1 = __builtin_bit_cast(unsigned short, h1);
    return ((unsigned)b1 << 16) | (unsigned)b0;
}

// ---------------------------------------------------------------------------
// Prep: one wave; lane k handles cluster k entirely in registers (~2 us).
// ---------------------------------------------------------------------------
__global__ __launch_bounds__(64) void gmm_prep(
    const float* __restrict__ pi, const float* __restrict__ mu,
    const float* __restrict__ Sigma, float* __restrict__ P)
{
    const int k = threadIdx.x;
    if (k >= K) return;

    float M[tri(D - 1, D - 1) + 1];   // 136 packed lower-tri

#pragma unroll
    for (int i = 0; i < D; ++i)
#pragma unroll
        for (int j = 0; j <= i; ++j)
            M[tri(i, j)] = Sigma[k * D * D + i * D + j];

    // Cholesky, packed, in place.
    float hl = 0.f;
#pragma unroll
    for (int j = 0; j < D; ++j) {
        float s = M[tri(j, j)];
#pragma unroll
        for (int p = 0; p < j; ++p) s -= M[tri(j, p)] * M[tri(j, p)];
        float ljj = sqrtf(s);
        M[tri(j, j)] = ljj;
        hl += logf(ljj);
        float inv = 1.f / ljj;
#pragma unroll
        for (int i = j + 1; i < D; ++i) {
            float t = M[tri(i, j)];
#pragma unroll
            for (int p = 0; p < j; ++p) t -= M[tri(i, p)] * M[tri(j, p)];
            M[tri(i, j)] = t * inv;
        }
    }

    // Invert lower-triangular in place (column j ascending).
#pragma unroll
    for (int j = 0; j < D; ++j) {
        float ujj = 1.f / M[tri(j, j)];
        M[tri(j, j)] = ujj;
#pragma unroll
        for (int i = j + 1; i < D; ++i) {
            float s = 0.f;
#pragma unroll
            for (int p = j; p < i; ++p) s += M[tri(i, p)] * M[tri(p, j)];
            M[tri(i, j)] = -s / M[tri(i, i)];
        }
    }

    const float invs2 = 0.70710678118654752440f;  // folds the 1/2 of maha
    float* Pk = P + k * PK_WORDS;
    unsigned* Pu = (unsigned*)Pk;

    Pk[0] = logf(pi[k]) - hl;
#pragma unroll
    for (int i = 0; i < D; ++i) {
        float acc = 0.f;
#pragma unroll
        for (int j = 0; j <= i; ++j) acc += M[tri(i, j)] * mu[k * D + j];
        Pk[1 + i] = -(acc * invs2);               // store -t'
    }
#pragma unroll
    for (int i = 0; i < D; ++i) {
        const int np = (i + 2) / 2;
#pragma unroll
        for (int p = 0; p < np; ++p) {
            float f0 = M[tri(i, 2 * p)] * invs2;
            float f1 = (2 * p + 1 <= i) ? M[tri(i, 2 * p + 1)] * invs2 : 0.f;
            Pu[17 + rowoff(i) + p] = pack2(f0, f1);
        }
    }
#pragma unroll
    for (int q = 89; q < PK_WORDS; ++q) Pu[q] = 0;
}

// ---------------------------------------------------------------------------
// Main: thread owns 4 points. Per-cluster logits via v_dot2_f32_f16
// (params f16-packed in LDS, broadcast reads). Per-point logits parked in
// LDS ([k][point] layout, lane-consecutive -> conflict-free) instead of a
// dynamically-indexed private array (which spilled to scratch in R1-R3).
// ---------------------------------------------------------------------------
__global__ __launch_bounds__(BLK) void gmm_main(
    const float* __restrict__ x, const float* __restrict__ P,
    float* __restrict__ out, int N)
{
    __shared__ float4 sPv[K * PK_WORDS / 4];          // 6 KB params
    __shared__ float  sRes[K][BLK * MPT];             // 16 KB logits
    float* sP = (float*)sPv;

    const int tid = threadIdx.x;
    const long long base = (long long)blockIdx.x * (BLK * MPT) + tid;

    // Issue x loads first so they overlap the param staging + barrier.
    long long n[MPT];
    bool ok[MPT];
    float4 xr[MPT][4];
#pragma unroll
    for (int m = 0; m < MPT; ++m) {
        n[m] = base + (long long)m * BLK;
        ok[m] = (n[m] < (long long)N);
        if (ok[m]) {
            const float4* p = (const float4*)(x + n[m] * D);
            xr[m][0] = p[0]; xr[m][1] = p[1]; xr[m][2] = p[2]; xr[m][3] = p[3];
        } else {
            float4 z = {0, 0, 0, 0};
            xr[m][0] = z; xr[m][1] = z; xr[m][2] = z; xr[m][3] = z;
        }
    }

    // Stage params to LDS (16B granules).
    const float4* Pv = (const float4*)P;
    for (int t = tid; t < K * PK_WORDS / 4; t += BLK) sPv[t] = Pv[t];
    __syncthreads();

    // Pack x into f16 pairs (RNE), 8 pairs per point.
    h2 xp[MPT][8];
#pragma unroll
    for (int m = 0; m < MPT; ++m)
#pragma unroll
        for (int q = 0; q < 4; ++q) {
            float4 a = xr[m][q];
            xp[m][2 * q]     = (h2){(_Float16)a.x, (_Float16)a.y};
            xp[m][2 * q + 1] = (h2){(_Float16)a.z, (_Float16)a.w};
        }

#pragma unroll 1          // k rolled: ~2.9 KB body stays I$-resident
    for (int k = 0; k < K; ++k) {
        const float* Pk = sP + k * PK_WORDS;
        const unsigned* Uk = (const unsigned*)(Pk + 17);
        float acc[MPT];
#pragma unroll
        for (int m = 0; m < MPT; ++m) acc[m] = 0.f;
#pragma unroll
        for (int i = 0; i < D; ++i) {
            const float nt = Pk[1 + i];
            float y[MPT];
#pragma unroll
            for (int m = 0; m < MPT; ++m) y[m] = nt;
            const int np = (i + 2) / 2;
#pragma unroll
            for (int p = 0; p < np; ++p) {
                h2 u = __builtin_bit_cast(h2, Uk[rowoff(i) + p]);
#pragma unroll
                for (int m = 0; m < MPT; ++m)
                    y[m] = fdot2f(u, xp[m][p], y[m]);
            }
#pragma unroll
            for (int m = 0; m < MPT; ++m) acc[m] = fmaf(y[m], y[m], acc[m]);
        }
        const float ck = Pk[0];
#pragma unroll
        for (int m = 0; m < MPT; ++m)
            sRes[k][m * BLK + tid] = ck - acc[m];   // lane-consecutive write
    }
    __syncthreads();   // sRes written by own thread only, but keep ordering w/ LDS reuse

    // Epilogue: statically-indexed read-back, register softmax, float4 stores.
#pragma unroll
    for (int m = 0; m < MPT; ++m) {
        float r[K];
#pragma unroll
        for (int k = 0; k < K; ++k) r[k] = sRes[k][m * BLK + tid];
        float mx = r[0];
#pragma unroll
        for (int k = 1; k < K; ++k) mx = fmaxf(mx, r[k]);
        float sum = 0.f;
#pragma unroll
        for (int k = 0; k < K; ++k) {
            float e = __expf(r[k] - mx);
            r[k] = e;
            sum += e;
        }
        float inv = 1.f / sum;
        if (ok[m]) {
            float4* po = (float4*)(out + n[m] * D);
            po[0] = (float4){r[0] * inv,  r[1] * inv,  r[2] * inv,  r[3] * inv};
            po[1] = (float4){r[4] * inv,  r[5] * inv,  r[6] * inv,  r[7] * inv};
            po[2] = (float4){r[8] * inv,  r[9] * inv,  r[10] * inv, r[11] * inv};
            po[3] = (float4){r[12] * inv, r[13] * inv, r[14] * inv, r[15] * inv};
        }
    }
}

extern "C" void kernel_launch(void* const* d_in, const int* in_sizes, int n_in,
                              void* d_out, int out_size, void* d_ws, size_t ws_size,
                              hipStream_t stream) {
    const float* x     = (const float*)d_in[0];   // (N, D)
    const float* pi    = (const float*)d_in[1];   // (1, K)
    const float* mu    = (const float*)d_in[2];   // (K, 1, D)
    const float* Sigma = (const float*)d_in[3];   // (K, D, D)
    float* out = (float*)d_out;                   // (N, K)
    const int N = in_sizes[0] / D;

    float* P = (float*)d_ws;                      // K * PK_WORDS dwords

    gmm_prep<<<1, 64, 0, stream>>>(pi, mu, Sigma, P);

    const int pts_per_blk = BLK * MPT;
    const int grid = (N + pts_per_blk - 1) / pts_per_blk;
    gmm_main<<<grid, BLK, 0, stream>>>(x, P, out, N);
}

// Round 6
// 118.559 us; speedup vs baseline: 1.1677x; 1.1677x over previous
//
#include <hip/hip_runtime.h>
#include <math.h>

#define D 16
#define K 16
#define BLK 256
#define PK_WORDS 96       // per-cluster param dwords (384 B)
// Param block per cluster k (dword units):
//   [0]      c_k           (f32)  log(pi_k) - sum(log diag L)
//   [1..16]  -t'_i         (f32)  t' = U' mu  (sign folded)
//   [17..88] U' rows       (2xf16 packed, rows padded to even length; 72 words)
//   [89..95] zero pad

typedef _Float16 h2 __attribute__((ext_vector_type(2)));

__host__ __device__ constexpr int tri(int i, int j) { return i * (i + 1) / 2 + j; }
__host__ __device__ constexpr int rowoff(int i) {   // pair-offset of row i
    int s = 0;
    for (int r = 0; r < i; ++r) s += (r + 2) / 2;   // ceil((r+1)/2)
    return s;
}

static __device__ __forceinline__ float fdot2f(h2 a, h2 b, float c) {
#if __has_builtin(__builtin_amdgcn_fdot2)
    return __builtin_amdgcn_fdot2(a, b, c, false);  // v_dot2_f32_f16
#else
    return fmaf((float)a.x, (float)b.x, fmaf((float)a.y, (float)b.y, c));
#endif
}

static __device__ __forceinline__ unsigned pack2(float f0, float f1) {
    _Float16 h0 = (_Float16)f0, h1 = (_Float16)f1;  // RNE converts
    unsigned short b0 = __builtin_bit_cast(unsigned short, h0);
    unsigned short b1 = __builtin_bit_cast(unsigned short, h1);
    return ((unsigned)b1 << 16) | (unsigned)b0;
}

// ---------------------------------------------------------------------------
// Prep: one wave; lane k handles cluster k entirely in registers (~2 us).
// ---------------------------------------------------------------------------
__global__ __launch_bounds__(64) void gmm_prep(
    const float* __restrict__ pi, const float* __restrict__ mu,
    const float* __restrict__ Sigma, float* __restrict__ P)
{
    const int k = threadIdx.x;
    if (k >= K) return;

    float M[tri(D - 1, D - 1) + 1];   // 136 packed lower-tri

#pragma unroll
    for (int i = 0; i < D; ++i)
#pragma unroll
        for (int j = 0; j <= i; ++j)
            M[tri(i, j)] = Sigma[k * D * D + i * D + j];

    // Cholesky, packed, in place.
    float hl = 0.f;
#pragma unroll
    for (int j = 0; j < D; ++j) {
        float s = M[tri(j, j)];
#pragma unroll
        for (int p = 0; p < j; ++p) s -= M[tri(j, p)] * M[tri(j, p)];
        float ljj = sqrtf(s);
        M[tri(j, j)] = ljj;
        hl += logf(ljj);
        float inv = 1.f / ljj;
#pragma unroll
        for (int i = j + 1; i < D; ++i) {
            float t = M[tri(i, j)];
#pragma unroll
            for (int p = 0; p < j; ++p) t -= M[tri(i, p)] * M[tri(j, p)];
            M[tri(i, j)] = t * inv;
        }
    }

    // Invert lower-triangular in place (column j ascending).
#pragma unroll
    for (int j = 0; j < D; ++j) {
        float ujj = 1.f / M[tri(j, j)];
        M[tri(j, j)] = ujj;
#pragma unroll
        for (int i = j + 1; i < D; ++i) {
            float s = 0.f;
#pragma unroll
            for (int p = j; p < i; ++p) s += M[tri(i, p)] * M[tri(p, j)];
            M[tri(i, j)] = -s / M[tri(i, i)];
        }
    }

    const float invs2 = 0.70710678118654752440f;  // folds the 1/2 of maha
    float* Pk = P + k * PK_WORDS;
    unsigned* Pu = (unsigned*)Pk;

    Pk[0] = logf(pi[k]) - hl;
#pragma unroll
    for (int i = 0; i < D; ++i) {
        float acc = 0.f;
#pragma unroll
        for (int j = 0; j <= i; ++j) acc += M[tri(i, j)] * mu[k * D + j];
        Pk[1 + i] = -(acc * invs2);               // store -t'
    }
#pragma unroll
    for (int i = 0; i < D; ++i) {
        const int np = (i + 2) / 2;
#pragma unroll
        for (int p = 0; p < np; ++p) {
            float f0 = M[tri(i, 2 * p)] * invs2;
            float f1 = (2 * p + 1 <= i) ? M[tri(i, 2 * p + 1)] * invs2 : 0.f;
            Pu[17 + rowoff(i) + p] = pack2(f0, f1);
        }
    }
#pragma unroll
    for (int q = 89; q < PK_WORDS; ++q) Pu[q] = 0;
}

// ---------------------------------------------------------------------------
// Main: one point per thread. Params arrive wave-uniform -> s_load on the
// scalar pipe (R2/R3-proven; zero VALU/LDS cost). k-loop FULLY UNROLLED so
// r[K] is statically indexed -> registers (R1-R3 spilled it to scratch,
// which both stalled the epilogue and capped occupancy). Math: f16
// v_dot2_f32_f16 with f32 accumulate (R4-proven, absmax 3.9e-3).
//   s_k = c_k - ||U'x - t'||^2 ; out = softmax_k(s_k)
// ---------------------------------------------------------------------------
__global__ __launch_bounds__(BLK) void gmm_main(
    const float* __restrict__ x, const float* __restrict__ P,
    float* __restrict__ out, int N)
{
    const int tid = threadIdx.x;
    const long long n = (long long)blockIdx.x * BLK + tid;
    const bool ok = n < (long long)N;

    float4 xr0 = {0, 0, 0, 0}, xr1 = xr0, xr2 = xr0, xr3 = xr0;
    if (ok) {
        const float4* p = (const float4*)(x + n * D);
        xr0 = p[0]; xr1 = p[1]; xr2 = p[2]; xr3 = p[3];
    }

    // x as 8 packed f16 pairs (RNE).
    h2 xp[8];
    xp[0] = (h2){(_Float16)xr0.x, (_Float16)xr0.y};
    xp[1] = (h2){(_Float16)xr0.z, (_Float16)xr0.w};
    xp[2] = (h2){(_Float16)xr1.x, (_Float16)xr1.y};
    xp[3] = (h2){(_Float16)xr1.z, (_Float16)xr1.w};
    xp[4] = (h2){(_Float16)xr2.x, (_Float16)xr2.y};
    xp[5] = (h2){(_Float16)xr2.z, (_Float16)xr2.w};
    xp[6] = (h2){(_Float16)xr3.x, (_Float16)xr3.y};
    xp[7] = (h2){(_Float16)xr3.z, (_Float16)xr3.w};

    float r[K];
#pragma unroll            // FULL unroll: static r[k], params at constant offsets
    for (int k = 0; k < K; ++k) {
        const float* __restrict__ Pk = P + k * PK_WORDS;      // uniform
        const unsigned* __restrict__ Uk = (const unsigned*)(Pk + 17);
        float acc = 0.f;
#pragma unroll
        for (int i = 0; i < D; ++i) {
            float y = Pk[1 + i];            // -t'_i  (s_load, const offset)
            const int np = (i + 2) / 2;
#pragma unroll
            for (int p = 0; p < np; ++p) {
                h2 u = __builtin_bit_cast(h2, Uk[rowoff(i) + p]);
                y = fdot2f(u, xp[p], y);
            }
            acc = fmaf(y, y, acc);
        }
        r[k] = Pk[0] - acc;
    }

    // Register softmax + coalesced float4 stores.
    float mx = r[0];
#pragma unroll
    for (int k = 1; k < K; ++k) mx = fmaxf(mx, r[k]);
    float sum = 0.f;
#pragma unroll
    for (int k = 0; k < K; ++k) {
        float e = __expf(r[k] - mx);
        r[k] = e;
        sum += e;
    }
    float inv = 1.f / sum;
    if (ok) {
        float4* po = (float4*)(out + n * D);
        po[0] = (float4){r[0] * inv,  r[1] * inv,  r[2] * inv,  r[3] * inv};
        po[1] = (float4){r[4] * inv,  r[5] * inv,  r[6] * inv,  r[7] * inv};
        po[2] = (float4){r[8] * inv,  r[9] * inv,  r[10] * inv, r[11] * inv};
        po[3] = (float4){r[12] * inv, r[13] * inv, r[14] * inv, r[15] * inv};
    }
}

extern "C" void kernel_launch(void* const* d_in, const int* in_sizes, int n_in,
                              void* d_out, int out_size, void* d_ws, size_t ws_size,
                              hipStream_t stream) {
    const float* x     = (const float*)d_in[0];   // (N, D)
    const float* pi    = (const float*)d_in[1];   // (1, K)
    const float* mu    = (const float*)d_in[2];   // (K, 1, D)
    const float* Sigma = (const float*)d_in[3];   // (K, D, D)
    float* out = (float*)d_out;                   // (N, K)
    const int N = in_sizes[0] / D;

    float* P = (float*)d_ws;                      // K * PK_WORDS dwords

    gmm_prep<<<1, 64, 0, stream>>>(pi, mu, Sigma, P);

    const int grid = (N + BLK - 1) / BLK;
    gmm_main<<<grid, BLK, 0, stream>>>(x, P, out, N);
}